// Round 8
// baseline (674.517 us; speedup 1.0000x reference)
//
#include <hip/hip_runtime.h>
#include <stdint.h>

// F=16, N=8192, D=64, K=512. fp32 in/out. Bit-exact numpy-fp32 emulation (R7-proven):
// dot = sequential-d fl(acc+fl(x*w)); xsq = pairwise-8 tree; wsq = sequential-d;
// dist = fl(fl(xsq - fl(2*dot)) + wsq); first-index argmin; STE fl(x + fl(q-x)).
// This round: LDS eliminated (wave-uniform rows from transposed W in d_ws -> s_load),
// pair-interleaved layout enables v_pk_* packed-f32 chains (2 codes per instr).
#define F_ 16
#define N_ 8192
#define D_ 64
#define K_ 512
#define KP (K_ / 2)   // 256 code pairs

typedef float v2f __attribute__((ext_vector_type(2)));

// prep: wtr[((f*KP + k/2)*D + d)*2 + (k&1)] = w[f][d][k]; wsq[f*K+k] = seq-d fl(w*w).
__global__ __launch_bounds__(256) void vq_prep(const float* __restrict__ w,
                                               float* __restrict__ wtr,
                                               float* __restrict__ wsq) {
    #pragma clang fp contract(off) reassociate(off)
    int i = blockIdx.x * 256 + threadIdx.x;   // one thread per (f,k)
    int f = i >> 9;
    int k = i & (K_ - 1);
    const float* wf = w + (size_t)f * D_ * K_;
    float* dst = wtr + (((size_t)f * KP + (k >> 1)) * D_) * 2 + (k & 1);
    float s = 0.f;
    #pragma unroll 8
    for (int d = 0; d < D_; ++d) {
        float v = wf[(size_t)d * K_ + k];     // coalesced over k
        dst[2 * d] = v;
        s = __fadd_rn(s, __fmul_rn(v, v));    // numpy seq-d reduce
    }
    wsq[(size_t)f * K_ + k] = s;
}

// main: 1 thread = 1 point. W rows wave-uniform from global (s_load path); packed chains.
__global__ __launch_bounds__(256, 2) void vq_main(const float* __restrict__ x,
                                                  const float* __restrict__ w,
                                                  const float* __restrict__ wtr,
                                                  const float* __restrict__ wsq,
                                                  float* __restrict__ out,
                                                  double* __restrict__ lacc) {
    #pragma clang fp contract(off) reassociate(off)
    const int tid = threadIdx.x;
    const int f = blockIdx.x >> 5;                      // 32 blocks per f
    const int point = blockIdx.x * 256 + tid;

    // x -> splatted packed registers: xpk[d] = (x[d], x[d])
    v2f xpk[D_];
    {
        const float4* xv = (const float4*)(x + (size_t)point * D_);
        #pragma unroll
        for (int i = 0; i < D_ / 4; ++i) {
            float4 u = xv[i];
            xpk[4*i+0] = (v2f){u.x, u.x}; xpk[4*i+1] = (v2f){u.y, u.y};
            xpk[4*i+2] = (v2f){u.z, u.z}; xpk[4*i+3] = (v2f){u.w, u.w};
        }
    }

    // xsq: numpy pairwise-8 tree (bit-exact, R7-verified)
    float xsq;
    {
        float r[8];
        #pragma unroll
        for (int j = 0; j < 8; ++j) r[j] = __fmul_rn(xpk[j].x, xpk[j].x);
        #pragma unroll
        for (int i = 8; i < 64; i += 8)
            #pragma unroll
            for (int j = 0; j < 8; ++j)
                r[j] = __fadd_rn(r[j], __fmul_rn(xpk[i+j].x, xpk[i+j].x));
        float c01 = __fadd_rn(r[0], r[1]), c23 = __fadd_rn(r[2], r[3]);
        float c45 = __fadd_rn(r[4], r[5]), c67 = __fadd_rn(r[6], r[7]);
        xsq = __fadd_rn(__fadd_rn(c01, c23), __fadd_rn(c45, c67));
    }

    const float* wtf = wtr + (size_t)f * KP * D_ * 2;   // uniform base
    const float* wqf = wsq + (size_t)f * K_;

    float best = 3.4e38f;
    int bestk = 0;

    #pragma unroll 2
    for (int jp = 0; jp < KP; ++jp) {
        const float4* rp = (const float4*)(wtf + (size_t)jp * (D_ * 2));  // uniform row pair
        v2f acc = (v2f){0.f, 0.f};
        #pragma unroll
        for (int i = 0; i < D_ / 2; ++i) {      // float4 = (wj[2i], wj1[2i], wj[2i+1], wj1[2i+1])
            float4 v = rp[i];
            v2f wa = (v2f){v.x, v.y};
            v2f wb = (v2f){v.z, v.w};
            acc = acc + xpk[2*i]     * wa;      // contract/reassoc off: fl(acc+fl(x*w)) per half
            acc = acc + xpk[2*i + 1] * wb;
        }
        float2 wq = *(const float2*)(wqf + 2 * jp);   // uniform
        float s0 = __fadd_rn(__fsub_rn(xsq, __fmul_rn(2.0f, acc.x)), wq.x);
        float s1 = __fadd_rn(__fsub_rn(xsq, __fmul_rn(2.0f, acc.y)), wq.y);
        if (s0 < best) { best = s0; bestk = 2*jp;     }   // first-index argmin order: j then j+1
        if (s1 < best) { best = s1; bestk = 2*jp + 1; }
    }

    // Gather raw codebook (divergent, L2-resident), STE out fl(x+fl(q-x)), fp64 loss acc.
    const float* wf = w + (size_t)f * D_ * K_;
    double lsum = 0.0;
    float ov[D_];
    #pragma unroll
    for (int d = 0; d < D_; ++d) {
        float q = wf[(size_t)d * K_ + bestk];
        float e = __fsub_rn(q, xpk[d].x);
        ov[d] = __fadd_rn(xpk[d].x, e);
        lsum += (double)__fmul_rn(e, e);
    }
    float4* ovv = (float4*)(out + (size_t)point * D_);
    #pragma unroll
    for (int i = 0; i < D_ / 4; ++i)
        ovv[i] = make_float4(ov[4*i+0], ov[4*i+1], ov[4*i+2], ov[4*i+3]);

    #pragma unroll
    for (int off = 32; off >= 1; off >>= 1)
        lsum += __shfl_down(lsum, off);
    if ((tid & 63) == 0)
        atomicAdd(lacc, lsum);
}

// loss = fl(m + fl(0.25*m)), m = fp32(mean) — identical to R7 (verified bit-exact)
__global__ void vq_finalize(const double* __restrict__ lacc, float* __restrict__ out) {
    #pragma clang fp contract(off)
    double m64 = lacc[0] / (double)((size_t)F_ * N_ * D_);
    float m = (float)m64;
    out[0] = __fadd_rn(m, __fmul_rn(0.25f, m));
}

extern "C" void kernel_launch(void* const* d_in, const int* in_sizes, int n_in,
                              void* d_out, int out_size, void* d_ws, size_t ws_size,
                              hipStream_t stream) {
    const float* x = (const float*)d_in[0];   // fp32 [F,N,D]
    const float* w = (const float*)d_in[1];   // fp32 [F,D,K]
    if (in_sizes[0] == F_ * D_ * K_ && in_sizes[1] == F_ * N_ * D_) {
        x = (const float*)d_in[1];
        w = (const float*)d_in[0];
    }
    float* out = (float*)d_out;               // fp32 [F*N*D + 1]

    // ws: wtr fp32 [F*K*D] (2 MB, pair-interleaved) | wsq fp32 [F*K] (128 KB) | lacc f64
    float*  wtr  = (float*)d_ws;
    float*  wsq  = (float*)((char*)d_ws + sizeof(float) * (size_t)F_ * K_ * D_);
    double* lacc = (double*)((char*)wsq + sizeof(float) * (size_t)F_ * K_);

    hipMemsetAsync(lacc, 0, sizeof(double), stream);
    vq_prep<<<(F_ * K_) / 256, 256, 0, stream>>>(w, wtr, wsq);
    vq_main<<<(F_ * N_) / 256, 256, 0, stream>>>(x, w, wtr, wsq, out, lacc);
    vq_finalize<<<1, 1, 0, stream>>>(lacc, out + (size_t)F_ * N_ * D_);
}

// Round 10
// 262.494 us; speedup vs baseline: 2.5696x; 2.5696x over previous
//
#include <hip/hip_runtime.h>
#include <stdint.h>

// F=16, N=8192, D=64, K=512. fp32 in/out. Bit-exact numpy-fp32 emulation (R7-proven):
// dot = sequential-d fl(acc+fl(x*w)); xsq = pairwise-8 tree; wsq = sequential-d;
// dist = fl(fl(xsq - fl(2*dot)) + wsq); first-index argmin; STE fl(x + fl(q-x)).
// R10: W broadcast via explicit SGPR s_load_dwordx16 (scalar pipe — no LDS/VMEM
// broadcast tax). Address laundered through readfirstlane so LLVM accepts "s"
// constraints (R9 failure: tid-derived addresses are divergent to LLVM).
// Row layout: 68 floats = [w[0..63], wsq, pad x3] -> one uniform base, imm offsets.
#define F_ 16
#define N_ 8192
#define D_ 64
#define K_ 512
#define WROW 68                      // floats per padded row (272 B, 16B-aligned)

typedef __attribute__((ext_vector_type(16))) float f16v;

// -------- prep: row-contiguous transpose + embedded wsq --------
__global__ __launch_bounds__(256) void vq_prep(const float* __restrict__ w,
                                               float* __restrict__ wt) {
    #pragma clang fp contract(off)
    int i = blockIdx.x * 256 + threadIdx.x;   // one thread per (f,k)
    int f = i >> 9;
    int k = i & (K_ - 1);
    const float* wf = w + (size_t)f * D_ * K_;
    float* dst = wt + ((size_t)f * K_ + k) * WROW;
    float s = 0.f;
    #pragma unroll 8
    for (int d = 0; d < D_; ++d) {
        float v = wf[(size_t)d * K_ + k];     // coalesced over k
        dst[d] = v;
        s = __fadd_rn(s, __fmul_rn(v, v));    // numpy seq-d reduce (R7-verified)
    }
    dst[D_] = s;                              // wsq embedded at row[64]
}

// -------- main: block = 128 points x 2 k-halves (4 waves). lane = point. --------
__global__ __launch_bounds__(256) void vq_main(const float* __restrict__ x,
                                               const float* __restrict__ wt,
                                               float* __restrict__ out,
                                               double* __restrict__ lacc) {
    #pragma clang fp contract(off)
    __shared__ unsigned long long keys[2][128];

    const int tid   = threadIdx.x;
    const int wave  = tid >> 6;
    const int lane  = tid & 63;
    const int khalf = wave & 1;                      // which 256-code half
    const int psub  = wave >> 1;                     // which 64-point sub-slice
    const int pidx  = (psub << 6) + lane;            // 0..127 within block
    const int point = blockIdx.x * 128 + pidx;
    const int f     = blockIdx.x >> 6;               // 64 blocks per f; uniform

    // x[point][:] -> lane-private registers
    float xr[D_];
    {
        const float4* xv = (const float4*)(x + (size_t)point * D_);
        #pragma unroll
        for (int i = 0; i < D_ / 4; ++i) {
            float4 u = xv[i];
            xr[4*i+0] = u.x; xr[4*i+1] = u.y; xr[4*i+2] = u.z; xr[4*i+3] = u.w;
        }
    }

    // xsq: numpy pairwise-8 tree (R7-verified bit-exact)
    float xsq;
    {
        float r[8];
        #pragma unroll
        for (int j = 0; j < 8; ++j) r[j] = __fmul_rn(xr[j], xr[j]);
        #pragma unroll
        for (int i = 8; i < 64; i += 8)
            #pragma unroll
            for (int j = 0; j < 8; ++j)
                r[j] = __fadd_rn(r[j], __fmul_rn(xr[i+j], xr[i+j]));
        float c01 = __fadd_rn(r[0], r[1]), c23 = __fadd_rn(r[2], r[3]);
        float c45 = __fadd_rn(r[4], r[5]), c67 = __fadd_rn(r[6], r[7]);
        xsq = __fadd_rn(__fadd_rn(c01, c23), __fadd_rn(c45, c67));
    }

    const float* wtf = wt + (size_t)f * K_ * WROW;
    const int j0 = khalf << 8;                       // 256 codes per half

    // Wave-uniform byte base for this half's first row, laundered to SGPRs.
    uint64_t a = (uint64_t)(wtf + (size_t)j0 * WROW);
    uint32_t alo = __builtin_amdgcn_readfirstlane((uint32_t)a);
    uint32_t ahi = __builtin_amdgcn_readfirstlane((uint32_t)(a >> 32));
    const uint64_t ubase = ((uint64_t)ahi << 32) | alo;

    float best  = 3.4e38f;
    int   bestj = j0;

    #pragma clang loop unroll(disable)
    for (int jj = 0; jj < 256; ++jj) {
        uint64_t ua = ubase + (uint64_t)jj * (WROW * 4);   // uniform scalar arithmetic
        f16v wa, wb, wc, wd;
        float wsqj;
        asm("s_load_dwordx16 %0, %5, 0x0\n\t"
            "s_load_dwordx16 %1, %5, 0x40\n\t"
            "s_load_dwordx16 %2, %5, 0x80\n\t"
            "s_load_dwordx16 %3, %5, 0xc0\n\t"
            "s_load_dword    %4, %5, 0x100\n\t"
            "s_waitcnt lgkmcnt(0)"
            : "=s"(wa), "=s"(wb), "=s"(wc), "=s"(wd), "=s"(wsqj)
            : "s"(ua));

        // numpy chain: acc = fl(acc + fl(x_d * w_d)), d ascending (R7 order)
        float acc = 0.f;
        #pragma unroll
        for (int i = 0; i < 16; ++i) acc = __fadd_rn(acc, __fmul_rn(xr[i],      wa[i]));
        #pragma unroll
        for (int i = 0; i < 16; ++i) acc = __fadd_rn(acc, __fmul_rn(xr[16 + i], wb[i]));
        #pragma unroll
        for (int i = 0; i < 16; ++i) acc = __fadd_rn(acc, __fmul_rn(xr[32 + i], wc[i]));
        #pragma unroll
        for (int i = 0; i < 16; ++i) acc = __fadd_rn(acc, __fmul_rn(xr[48 + i], wd[i]));

        float s = __fadd_rn(__fsub_rn(xsq, __fmul_rn(2.0f, acc)), wsqj);
        if (s < best) { best = s; bestj = j0 + jj; } // strict '<': first-index argmin
    }

    // Distances are strictly positive here (||x||^2 ~ 64 dominates), so float bits are
    // order-preserving: key = (valbits<<32)|k; min-key = (min val, then min k).
    keys[khalf][pidx] = ((unsigned long long)__float_as_uint(best) << 32)
                        | (unsigned int)bestj;
    __syncthreads();

    // -------- merge + epilogue: threads 0..127 own one point each --------
    double lsum = 0.0;
    if (tid < 128) {
        unsigned long long k0 = keys[0][tid], k1 = keys[1][tid];
        unsigned long long kk = (k0 <= k1) ? k0 : k1;   // equal val => lower k wins
        int bestk = (int)(kk & 0xffffffffu);
        int p = blockIdx.x * 128 + tid;

        const float* xrow = x + (size_t)p * D_;
        const float* qrow = wtf + (size_t)bestk * WROW; // exact copies of w values
        float4* ov = (float4*)(out + (size_t)p * D_);
        #pragma unroll
        for (int i = 0; i < D_ / 4; ++i) {
            float4 q  = ((const float4*)qrow)[i];
            float4 xv = ((const float4*)xrow)[i];
            float e0 = __fsub_rn(q.x, xv.x), e1 = __fsub_rn(q.y, xv.y);
            float e2 = __fsub_rn(q.z, xv.z), e3 = __fsub_rn(q.w, xv.w);
            float4 o;
            o.x = __fadd_rn(xv.x, e0); o.y = __fadd_rn(xv.y, e1);
            o.z = __fadd_rn(xv.z, e2); o.w = __fadd_rn(xv.w, e3);
            ov[i] = o;
            lsum += (double)__fmul_rn(e0, e0);
            lsum += (double)__fmul_rn(e1, e1);
            lsum += (double)__fmul_rn(e2, e2);
            lsum += (double)__fmul_rn(e3, e3);
        }
    }
    // wave reduce (lanes with no point contribute 0), one atomic per wave
    #pragma unroll
    for (int off = 32; off >= 1; off >>= 1)
        lsum += __shfl_down(lsum, off);
    if (lane == 0)
        atomicAdd(lacc, lsum);
}

// loss = fl(m + fl(0.25*m)), m = fp32(mean) — R7-verified
__global__ void vq_finalize(const double* __restrict__ lacc, float* __restrict__ out) {
    #pragma clang fp contract(off)
    double m64 = lacc[0] / (double)((size_t)F_ * N_ * D_);
    float m = (float)m64;
    out[0] = __fadd_rn(m, __fmul_rn(0.25f, m));
}

extern "C" void kernel_launch(void* const* d_in, const int* in_sizes, int n_in,
                              void* d_out, int out_size, void* d_ws, size_t ws_size,
                              hipStream_t stream) {
    const float* x = (const float*)d_in[0];   // fp32 [F,N,D]
    const float* w = (const float*)d_in[1];   // fp32 [F,D,K]
    if (in_sizes[0] == F_ * D_ * K_ && in_sizes[1] == F_ * N_ * D_) {
        x = (const float*)d_in[1];
        w = (const float*)d_in[0];
    }
    float* out = (float*)d_out;               // fp32 [F*N*D + 1]

    // ws: wt fp32 [F*K*WROW] (~2.23 MB, padded rows w/ embedded wsq) | lacc f64
    float*  wt   = (float*)d_ws;
    double* lacc = (double*)((char*)d_ws + sizeof(float) * (size_t)F_ * K_ * WROW);

    hipMemsetAsync(lacc, 0, sizeof(double), stream);
    vq_prep<<<(F_ * K_) / 256, 256, 0, stream>>>(w, wt);
    vq_main<<<(F_ * N_) / 128, 256, 0, stream>>>(x, wt, out, lacc);
    vq_finalize<<<1, 1, 0, stream>>>(lacc, out + (size_t)F_ * N_ * D_);
}

// Round 12
// 243.263 us; speedup vs baseline: 2.7728x; 1.0791x over previous
//
#include <hip/hip_runtime.h>
#include <stdint.h>

// F=16, N=8192, D=64, K=512. fp32 in/out. Bit-exact numpy-fp32 emulation (R7/R10-proven):
// dot = sequential-d fl(acc+fl(x*w)); xsq = pairwise-8 tree; wsq = sequential-d;
// dist = fl(fl(xsq - fl(2*dot)) + wsq); first-index argmin; STE fl(x + fl(q-x)).
// R12 = R10 with a 4-way K-split (2048 blocks -> 8 waves/SIMD, doubling occupancy).
// W broadcast via SGPR s_load (R10-proven asm); per-lane u64 (score,idx) keys;
// 4-way LDS merge (R10 proved the 2-way u64-key merge bit-exact).
#define F_ 16
#define N_ 8192
#define D_ 64
#define K_ 512
#define WROW 68                      // floats per padded row: [w[0..63], wsq, pad x3]

typedef __attribute__((ext_vector_type(16))) float f16v;

// -------- prep: row transpose + embedded seq-d wsq (UNCHANGED from R10) --------
__global__ __launch_bounds__(256) void vq_prep(const float* __restrict__ w,
                                               float* __restrict__ wt) {
    #pragma clang fp contract(off)
    int i = blockIdx.x * 256 + threadIdx.x;   // one thread per (f,k)
    int f = i >> 9;
    int k = i & (K_ - 1);
    const float* wf = w + (size_t)f * D_ * K_;
    float* dst = wt + ((size_t)f * K_ + k) * WROW;
    float s = 0.f;
    #pragma unroll 8
    for (int d = 0; d < D_; ++d) {
        float v = wf[(size_t)d * K_ + k];     // coalesced over k
        dst[d] = v;
        s = __fadd_rn(s, __fmul_rn(v, v));    // numpy seq-d reduce (R7-verified)
    }
    dst[D_] = s;                              // wsq embedded at row[64]
}

// -------- main: block = 64 points x 4 K-quarters (4 waves); lane = point --------
__global__ __launch_bounds__(256) void vq_main(const float* __restrict__ x,
                                               const float* __restrict__ wt,
                                               float* __restrict__ out,
                                               double* __restrict__ lacc) {
    #pragma clang fp contract(off)
    __shared__ unsigned long long keys[4][64];

    const int tid  = threadIdx.x;
    const int kq   = tid >> 6;                       // K-quarter 0..3
    const int lane = tid & 63;
    const int point = blockIdx.x * 64 + lane;
    const int f     = blockIdx.x >> 7;               // 128 blocks per f; uniform

    // x[point][:] -> lane-private registers (each wave loads the same 64 points)
    float xr[D_];
    {
        const float4* xv = (const float4*)(x + (size_t)point * D_);
        #pragma unroll
        for (int i = 0; i < D_ / 4; ++i) {
            float4 u = xv[i];
            xr[4*i+0] = u.x; xr[4*i+1] = u.y; xr[4*i+2] = u.z; xr[4*i+3] = u.w;
        }
    }

    // xsq: numpy pairwise-8 tree (R7-verified bit-exact)
    float xsq;
    {
        float r[8];
        #pragma unroll
        for (int j = 0; j < 8; ++j) r[j] = __fmul_rn(xr[j], xr[j]);
        #pragma unroll
        for (int i = 8; i < 64; i += 8)
            #pragma unroll
            for (int j = 0; j < 8; ++j)
                r[j] = __fadd_rn(r[j], __fmul_rn(xr[i+j], xr[i+j]));
        float c01 = __fadd_rn(r[0], r[1]), c23 = __fadd_rn(r[2], r[3]);
        float c45 = __fadd_rn(r[4], r[5]), c67 = __fadd_rn(r[6], r[7]);
        xsq = __fadd_rn(__fadd_rn(c01, c23), __fadd_rn(c45, c67));
    }

    const float* wtf = wt + (size_t)f * K_ * WROW;
    const int j0 = kq << 7;                          // 128 codes per quarter

    // Wave-uniform byte base, laundered to SGPRs (R10-proven pattern).
    uint64_t a = (uint64_t)(wtf + (size_t)j0 * WROW);
    uint32_t alo = __builtin_amdgcn_readfirstlane((uint32_t)a);
    uint32_t ahi = __builtin_amdgcn_readfirstlane((uint32_t)(a >> 32));
    const uint64_t ubase = ((uint64_t)ahi << 32) | alo;

    float best  = 3.4e38f;
    int   bestj = j0;

    #pragma clang loop unroll(disable)
    for (int jj = 0; jj < 128; ++jj) {
        uint64_t ua = ubase + (uint64_t)jj * (WROW * 4);   // uniform scalar arithmetic
        f16v wa, wb, wc, wd;
        float wsqj;
        asm("s_load_dwordx16 %0, %5, 0x0\n\t"
            "s_load_dwordx16 %1, %5, 0x40\n\t"
            "s_load_dwordx16 %2, %5, 0x80\n\t"
            "s_load_dwordx16 %3, %5, 0xc0\n\t"
            "s_load_dword    %4, %5, 0x100\n\t"
            "s_waitcnt lgkmcnt(0)"
            : "=s"(wa), "=s"(wb), "=s"(wc), "=s"(wd), "=s"(wsqj)
            : "s"(ua));

        // EXACT numpy chain: acc = fl(acc + fl(x_d * w_d)), d ascending (R7 order)
        float acc = 0.f;
        #pragma unroll
        for (int i = 0; i < 16; ++i) acc = __fadd_rn(acc, __fmul_rn(xr[i],      wa[i]));
        #pragma unroll
        for (int i = 0; i < 16; ++i) acc = __fadd_rn(acc, __fmul_rn(xr[16 + i], wb[i]));
        #pragma unroll
        for (int i = 0; i < 16; ++i) acc = __fadd_rn(acc, __fmul_rn(xr[32 + i], wc[i]));
        #pragma unroll
        for (int i = 0; i < 16; ++i) acc = __fadd_rn(acc, __fmul_rn(xr[48 + i], wd[i]));

        float s = __fadd_rn(__fsub_rn(xsq, __fmul_rn(2.0f, acc)), wsqj);
        if (s < best) { best = s; bestj = j0 + jj; } // strict '<': first-index argmin
    }

    // Distances are strictly positive (xsq ~ 64 dominates), so float bits are order-
    // preserving: key = (valbits<<32)|idx; u64 min = (min score, then min idx).
    keys[kq][lane] = ((unsigned long long)__float_as_uint(best) << 32)
                     | (unsigned int)bestj;
    __syncthreads();

    // -------- 4-way merge + epilogue: wave 0, lane = point (R10-proven ops) --------
    double lsum = 0.0;
    if (tid < 64) {
        unsigned long long kk = keys[0][lane];
        #pragma unroll
        for (int q = 1; q < 4; ++q)
            kk = (keys[q][lane] < kk) ? keys[q][lane] : kk;
        int bestk = (int)(kk & 0xffffffffu);

        const float* qrow = wtf + (size_t)bestk * WROW;  // exact copies of w values
        float4* ov = (float4*)(out + (size_t)point * D_);
        #pragma unroll
        for (int i = 0; i < D_ / 4; ++i) {
            float4 q = ((const float4*)qrow)[i];
            float e0 = __fsub_rn(q.x, xr[4*i+0]), e1 = __fsub_rn(q.y, xr[4*i+1]);
            float e2 = __fsub_rn(q.z, xr[4*i+2]), e3 = __fsub_rn(q.w, xr[4*i+3]);
            float4 o;
            o.x = __fadd_rn(xr[4*i+0], e0); o.y = __fadd_rn(xr[4*i+1], e1);
            o.z = __fadd_rn(xr[4*i+2], e2); o.w = __fadd_rn(xr[4*i+3], e3);
            ov[i] = o;
            lsum += (double)__fmul_rn(e0, e0);
            lsum += (double)__fmul_rn(e1, e1);
            lsum += (double)__fmul_rn(e2, e2);
            lsum += (double)__fmul_rn(e3, e3);
        }
    }
    // wave reduce (waves 1-3 contribute 0), single atomic from tid 0
    #pragma unroll
    for (int off = 32; off >= 1; off >>= 1)
        lsum += __shfl_down(lsum, off);
    if (tid == 0)
        atomicAdd(lacc, lsum);
}

// loss = fl(m + fl(0.25*m)), m = fp32(mean) — R7-verified
__global__ void vq_finalize(const double* __restrict__ lacc, float* __restrict__ out) {
    #pragma clang fp contract(off)
    double m64 = lacc[0] / (double)((size_t)F_ * N_ * D_);
    float m = (float)m64;
    out[0] = __fadd_rn(m, __fmul_rn(0.25f, m));
}

extern "C" void kernel_launch(void* const* d_in, const int* in_sizes, int n_in,
                              void* d_out, int out_size, void* d_ws, size_t ws_size,
                              hipStream_t stream) {
    const float* x = (const float*)d_in[0];   // fp32 [F,N,D]
    const float* w = (const float*)d_in[1];   // fp32 [F,D,K]
    if (in_sizes[0] == F_ * D_ * K_ && in_sizes[1] == F_ * N_ * D_) {
        x = (const float*)d_in[1];
        w = (const float*)d_in[0];
    }
    float* out = (float*)d_out;               // fp32 [F*N*D + 1]

    // ws: wt fp32 [F*K*WROW] (~2.23 MB, padded rows w/ embedded wsq) | lacc f64
    float*  wt   = (float*)d_ws;
    double* lacc = (double*)((char*)d_ws + sizeof(float) * (size_t)F_ * K_ * WROW);

    hipMemsetAsync(lacc, 0, sizeof(double), stream);
    vq_prep<<<(F_ * K_) / 256, 256, 0, stream>>>(w, wt);
    vq_main<<<(F_ * N_) / 64, 256, 0, stream>>>(x, wt, out, lacc);
    vq_finalize<<<1, 1, 0, stream>>>(lacc, out + (size_t)F_ * N_ * D_);
}